// Round 2
// baseline (1674.971 us; speedup 1.0000x reference)
//
#include <hip/hip_runtime.h>

__device__ __forceinline__ float sigf(float v) {
    return 1.0f / (1.0f + __expf(-v));
}
__device__ __forceinline__ float tanh_fast(float v) {
    return 1.0f - 2.0f / (__expf(2.0f * v) + 1.0f);
}

// 256-thread blocks (4 waves), block b owns rows [b*64, b*64+64).
// Occupancy: 1024 blocks = 4 blocks/CU x 4 waves = 16 waves/CU (2x previous),
// doubling in-flight memory per CU (theory: BW is MLP-limited, not
// pattern-limited -- round-1 interleave experiment showed BW invariant to
// address distribution at fixed wave count).
// Phase A: wave 0 computes the small net for all 64 rows (lane k = row k,
// zero lane duplication, 4x less total phase-A VALU than before) -> o2 to LDS.
// Waves 1-3 overlap their constant loads + first H prefetch with phase A.
// Phase B: each wave streams its 16 rows; whole-wave coalesced 1KB loads,
// fold over l with sigmoid(decays) in VGPRs, W_read slice in VGPRs,
// 6-level shfl_xor butterfly, lane rr stores its row (+ o2 from LDS).
__global__ __launch_bounds__(256, 4)
void organism_main(const float* __restrict__ x,
                   const float* __restrict__ H,
                   const float* __restrict__ W_bit,
                   const float* __restrict__ b_bit,
                   const float* __restrict__ W_bridge,
                   const float* __restrict__ W_read,
                   const float* __restrict__ b_read,
                   const float* __restrict__ W_sh,
                   const float* __restrict__ b_sh,
                   const float* __restrict__ W_eng,
                   const float* __restrict__ b_eng,
                   const float* __restrict__ W_imp,
                   const float* __restrict__ b_imp,
                   const float* __restrict__ W_sur,
                   const float* __restrict__ b_sur,
                   const float* __restrict__ W_gate,
                   const float* __restrict__ b_gate,
                   const float* __restrict__ decays,
                   const float* __restrict__ halt_w,
                   const float* __restrict__ halt_b,
                   float* __restrict__ out)
{
    const int tid  = threadIdx.x;            // 0..255
    const int wave = tid >> 6;               // 0..3
    const int lane = tid & 63;               // 0..63
    const size_t rowblk = (size_t)blockIdx.x * 64;

    __shared__ float o2_lds[64][8];

    // ================= phase A: wave 0 only, 64 rows (one per lane) =======
    if (wave == 0) {
        const size_t arow = rowblk + lane;
        float xv[8];
        const float4 x0 = *(const float4*)(x + arow * 8);
        const float4 x1 = *(const float4*)(x + arow * 8 + 4);
        xv[0]=x0.x; xv[1]=x0.y; xv[2]=x0.z; xv[3]=x0.w;
        xv[4]=x1.x; xv[5]=x1.y; xv[6]=x1.z; xv[7]=x1.w;

        float s1[32];
#pragma unroll
        for (int i = 0; i < 32; ++i) {
            float a = b_bit[i];
#pragma unroll
            for (int k = 0; k < 8; ++k) a += W_bit[i*8+k] * xv[k];
            s1[i] = a;
        }

        float sa = b_sur[0], ga = b_gate[0];
#pragma unroll
        for (int i = 0; i < 32; ++i) {
            sa += W_sur[i]  * s1[i];
            ga += W_gate[i] * s1[i];
        }
        const float sur = sigf(sa) * sigf(ga);

        float s2[64];
#pragma unroll
        for (int m = 0; m < 64; ++m) {
            float a = 0.0f;
#pragma unroll
            for (int i = 0; i < 32; ++i) a += W_bridge[m*32+i] * s1[i];
            s2[m] = tanh_fast(a);
        }

        float ea = b_eng[0], ia = b_imp[0];
        for (int n = 0; n < 64; ++n) {
            float a = b_sh[n];
#pragma unroll
            for (int m = 0; m < 64; ++m) a += W_sh[n*64+m] * s2[m];
            a = fmaxf(a, 0.0f);
            ea += W_eng[n] * a;
            ia += W_imp[n] * a;
        }
        // hoist sur out of the W_read dot product (wv[m] = sur*s2[m] removed)
        const float eis = 0.25f * sigf(ea) * sigf(ia) * sur;

        float o2[8];
#pragma unroll
        for (int o = 0; o < 8; ++o) o2[o] = b_read[o];
        for (int r = 0; r < 8; ++r) {
            float hs = 0.0f;
#pragma unroll
            for (int l = 0; l < 4; ++l) {
                float a = halt_b[l];
#pragma unroll
                for (int m = 0; m < 64; ++m) a += halt_w[(l*8+r)*64+m] * s2[m];
                hs += sigf(a);
            }
            const float grs = eis * hs;
#pragma unroll
            for (int o = 0; o < 8; ++o) {
                float p = 0.0f;
#pragma unroll
                for (int m = 0; m < 64; ++m) p += W_read[o*512 + r*64 + m] * s2[m];
                o2[o] += grs * p;
            }
        }
        *(float4*)&o2_lds[lane][0] = make_float4(o2[0], o2[1], o2[2], o2[3]);
        *(float4*)&o2_lds[lane][4] = make_float4(o2[4], o2[5], o2[6], o2[7]);
    }

    // ========== per-lane constants (fixed across rows and l) ==============
    // slot s = hf*4+c  <->  rm = hf*256 + lane*4 + c
    float sd[4][8];
#pragma unroll
    for (int l = 0; l < 4; ++l)
#pragma unroll
        for (int hf = 0; hf < 2; ++hf) {
            const float4 d = *(const float4*)(decays + l*512 + hf*256 + lane*4);
            sd[l][hf*4+0] = 0.25f * sigf(d.x);
            sd[l][hf*4+1] = 0.25f * sigf(d.y);
            sd[l][hf*4+2] = 0.25f * sigf(d.z);
            sd[l][hf*4+3] = 0.25f * sigf(d.w);
        }
    float wrv[8][8];
#pragma unroll
    for (int o = 0; o < 8; ++o)
#pragma unroll
        for (int hf = 0; hf < 2; ++hf) {
            const float4 wq = *(const float4*)(W_read + o*512 + hf*256 + lane*4);
            wrv[o][hf*4+0] = wq.x;
            wrv[o][hf*4+1] = wq.y;
            wrv[o][hf*4+2] = wq.z;
            wrv[o][hf*4+3] = wq.w;
        }

    // ---- issue H prefetch for this wave's first row -----------------------
    const size_t wrow0 = rowblk + (size_t)wave * 16;
    const float* __restrict__ Hl = H + wrow0 * 2048 + lane * 4;
    float4 h[8];
#pragma unroll
    for (int it = 0; it < 8; ++it)
        h[it] = *(const float4*)(Hl + it * 256);

    __syncthreads();   // o2_lds ready

    // ================= phase B: each wave streams its 16 rows ==============
#pragma unroll 1
    for (int rr = 0; rr < 16; ++rr) {
        // fold over l: g[slot] = sum_l sd[l][slot] * H[l][rm(slot)]
        float g[8];
#pragma unroll
        for (int hf = 0; hf < 2; ++hf) {
            g[hf*4+0] = sd[0][hf*4+0]*h[hf].x   + sd[1][hf*4+0]*h[2+hf].x
                      + sd[2][hf*4+0]*h[4+hf].x + sd[3][hf*4+0]*h[6+hf].x;
            g[hf*4+1] = sd[0][hf*4+1]*h[hf].y   + sd[1][hf*4+1]*h[2+hf].y
                      + sd[2][hf*4+1]*h[4+hf].y + sd[3][hf*4+1]*h[6+hf].y;
            g[hf*4+2] = sd[0][hf*4+2]*h[hf].z   + sd[1][hf*4+2]*h[2+hf].z
                      + sd[2][hf*4+2]*h[4+hf].z + sd[3][hf*4+2]*h[6+hf].z;
            g[hf*4+3] = sd[0][hf*4+3]*h[hf].w   + sd[1][hf*4+3]*h[2+hf].w
                      + sd[2][hf*4+3]*h[4+hf].w + sd[3][hf*4+3]*h[6+hf].w;
        }

        // prefetch next row's H (h is dead after g); wraps on last iter
        {
            const int nrr = (rr + 1) & 15;
            const float* __restrict__ nb = H + (wrow0 + nrr) * 2048 + lane * 4;
#pragma unroll
            for (int it = 0; it < 8; ++it)
                h[it] = *(const float4*)(nb + it * 256);
        }

        // apply W_read slice
        float acc[8];
#pragma unroll
        for (int o = 0; o < 8; ++o) {
            float a = 0.0f;
#pragma unroll
            for (int s = 0; s < 8; ++s) a += wrv[o][s] * g[s];
            acc[o] = a;
        }

        // 6-level butterfly: every lane ends with the full row sums
#pragma unroll
        for (int m = 1; m <= 32; m <<= 1) {
#pragma unroll
            for (int o = 0; o < 8; ++o)
                acc[o] += __shfl_xor(acc[o], m, 64);
        }

        if (lane == rr) {
            const int lrow = wave * 16 + rr;
            const float4 oA = *(const float4*)&o2_lds[lrow][0];
            const float4 oB = *(const float4*)&o2_lds[lrow][4];
            float4 a0, a1;
            a0.x = acc[0] + oA.x; a0.y = acc[1] + oA.y;
            a0.z = acc[2] + oA.z; a0.w = acc[3] + oA.w;
            a1.x = acc[4] + oB.x; a1.y = acc[5] + oB.y;
            a1.z = acc[6] + oB.z; a1.w = acc[7] + oB.w;
            float* op = out + (rowblk + lrow) * 8;
            *(float4*)(op)     = a0;
            *(float4*)(op + 4) = a1;
        }
    }
}

extern "C" void kernel_launch(void* const* d_in, const int* in_sizes, int n_in,
                              void* d_out, int out_size, void* d_ws, size_t ws_size,
                              hipStream_t stream) {
    (void)n_in; (void)d_ws; (void)ws_size; (void)out_size;
    const float* x        = (const float*)d_in[0];
    const float* H        = (const float*)d_in[1];
    const float* W_bit    = (const float*)d_in[2];
    const float* b_bit    = (const float*)d_in[3];
    const float* W_bridge = (const float*)d_in[4];
    const float* W_read   = (const float*)d_in[5];
    const float* b_read   = (const float*)d_in[6];
    const float* W_sh     = (const float*)d_in[7];
    const float* b_sh     = (const float*)d_in[8];
    const float* W_eng    = (const float*)d_in[9];
    const float* b_eng    = (const float*)d_in[10];
    const float* W_imp    = (const float*)d_in[11];
    const float* b_imp    = (const float*)d_in[12];
    const float* W_sur    = (const float*)d_in[13];
    const float* b_sur    = (const float*)d_in[14];
    const float* W_gate   = (const float*)d_in[15];
    const float* b_gate   = (const float*)d_in[16];
    const float* decays   = (const float*)d_in[17];
    const float* halt_w   = (const float*)d_in[18];
    const float* halt_b   = (const float*)d_in[19];
    float* out = (float*)d_out;

    const int B = in_sizes[1] / 2048;            // H is [B, 4*8*16*4]
    hipLaunchKernelGGL(organism_main, dim3(B / 64), dim3(256), 0, stream,
                       x, H, W_bit, b_bit, W_bridge, W_read, b_read,
                       W_sh, b_sh, W_eng, b_eng, W_imp, b_imp,
                       W_sur, b_sur, W_gate, b_gate, decays, halt_w, halt_b,
                       out);
}

// Round 3
// 959.402 us; speedup vs baseline: 1.7458x; 1.7458x over previous
//
#include <hip/hip_runtime.h>

__device__ __forceinline__ float sigf(float v) {
    return 1.0f / (1.0f + __expf(-v));
}
__device__ __forceinline__ float tanh_fast(float v) {
    return 1.0f - 2.0f / (__expf(2.0f * v) + 1.0f);
}

// ============================================================================
// Kernel A: per-row small network (term2 + b_read) -> out[row][0..8).
// One thread per row; compute-bound (~25k FLOP/row, 1.7 GFLOP total ~15-25us).
// Register-heavy (s1[32]+s2[64]) but isolated from the streaming kernel, so
// its pressure can't force spills in the memory-bound hot loop (round-2 bug).
// ============================================================================
__global__ __launch_bounds__(256)
void organism_smallnet(const float* __restrict__ x,
                       const float* __restrict__ W_bit,
                       const float* __restrict__ b_bit,
                       const float* __restrict__ W_bridge,
                       const float* __restrict__ W_read,
                       const float* __restrict__ b_read,
                       const float* __restrict__ W_sh,
                       const float* __restrict__ b_sh,
                       const float* __restrict__ W_eng,
                       const float* __restrict__ b_eng,
                       const float* __restrict__ W_imp,
                       const float* __restrict__ b_imp,
                       const float* __restrict__ W_sur,
                       const float* __restrict__ b_sur,
                       const float* __restrict__ W_gate,
                       const float* __restrict__ b_gate,
                       const float* __restrict__ halt_w,
                       const float* __restrict__ halt_b,
                       float* __restrict__ out)
{
    const size_t row = (size_t)blockIdx.x * 256 + threadIdx.x;

    float xv[8];
    const float4 x0 = *(const float4*)(x + row * 8);
    const float4 x1 = *(const float4*)(x + row * 8 + 4);
    xv[0]=x0.x; xv[1]=x0.y; xv[2]=x0.z; xv[3]=x0.w;
    xv[4]=x1.x; xv[5]=x1.y; xv[6]=x1.z; xv[7]=x1.w;

    float s1[32];
#pragma unroll
    for (int i = 0; i < 32; ++i) {
        float a = b_bit[i];
#pragma unroll
        for (int k = 0; k < 8; ++k) a += W_bit[i*8+k] * xv[k];
        s1[i] = a;
    }

    float sa = b_sur[0], ga = b_gate[0];
#pragma unroll
    for (int i = 0; i < 32; ++i) {
        sa += W_sur[i]  * s1[i];
        ga += W_gate[i] * s1[i];
    }
    const float sur = sigf(sa) * sigf(ga);

    float s2[64];
#pragma unroll
    for (int m = 0; m < 64; ++m) {
        float a = 0.0f;
#pragma unroll
        for (int i = 0; i < 32; ++i) a += W_bridge[m*32+i] * s1[i];
        s2[m] = tanh_fast(a);
    }

    float ea = b_eng[0], ia = b_imp[0];
    for (int n = 0; n < 64; ++n) {
        float a = b_sh[n];
#pragma unroll
        for (int m = 0; m < 64; ++m) a += W_sh[n*64+m] * s2[m];
        a = fmaxf(a, 0.0f);
        ea += W_eng[n] * a;
        ia += W_imp[n] * a;
    }
    // hoist sur out of the W_read dot product
    const float eis = 0.25f * sigf(ea) * sigf(ia) * sur;

    float o2[8];
#pragma unroll
    for (int o = 0; o < 8; ++o) o2[o] = b_read[o];
    for (int r = 0; r < 8; ++r) {
        float hs = 0.0f;
#pragma unroll
        for (int l = 0; l < 4; ++l) {
            float a = halt_b[l];
#pragma unroll
            for (int m = 0; m < 64; ++m) a += halt_w[(l*8+r)*64+m] * s2[m];
            hs += sigf(a);
        }
        const float grs = eis * hs;
#pragma unroll
        for (int o = 0; o < 8; ++o) {
            float p = 0.0f;
#pragma unroll
            for (int m = 0; m < 64; ++m) p += W_read[o*512 + r*64 + m] * s2[m];
            o2[o] += grs * p;
        }
    }

    *(float4*)(out + row * 8)     = make_float4(o2[0], o2[1], o2[2], o2[3]);
    *(float4*)(out + row * 8 + 4) = make_float4(o2[4], o2[5], o2[6], o2[7]);
}

// ============================================================================
// Kernel B: streaming H contraction (term1), adds into out.
// 128-thread blocks (2 waves), 32 rows/block (16/wave).
// __launch_bounds__(128,4): 4 waves/EU min -> 8 blocks/CU = 16 waves/CU
// (2x round-0's grid-capped 8) with VGPR <= 128 (round-0 phase-B structure
// measured 124 incl. phase A, so phase-B-only fits without spills).
// Theory: delivered BW is ~0.75 GB/s per resident wave (invariant across
// r0/r1/copy-ubench) => 2x waves => 2x BW.
// ============================================================================
__global__ __launch_bounds__(128, 4)
void organism_stream(const float* __restrict__ H,
                     const float* __restrict__ W_read,
                     const float* __restrict__ decays,
                     float* __restrict__ out)
{
    const int lane = threadIdx.x & 63;       // 0..63
    const int wave = threadIdx.x >> 6;       // 0..1
    const size_t wrow0 = (size_t)blockIdx.x * 32 + (size_t)wave * 16;

    // per-lane constants: slot s = hf*4+c  <->  rm = hf*256 + lane*4 + c
    float sd[4][8];
#pragma unroll
    for (int l = 0; l < 4; ++l)
#pragma unroll
        for (int hf = 0; hf < 2; ++hf) {
            const float4 d = *(const float4*)(decays + l*512 + hf*256 + lane*4);
            sd[l][hf*4+0] = 0.25f * sigf(d.x);
            sd[l][hf*4+1] = 0.25f * sigf(d.y);
            sd[l][hf*4+2] = 0.25f * sigf(d.z);
            sd[l][hf*4+3] = 0.25f * sigf(d.w);
        }
    float wrv[8][8];
#pragma unroll
    for (int o = 0; o < 8; ++o)
#pragma unroll
        for (int hf = 0; hf < 2; ++hf) {
            const float4 wq = *(const float4*)(W_read + o*512 + hf*256 + lane*4);
            wrv[o][hf*4+0] = wq.x;
            wrv[o][hf*4+1] = wq.y;
            wrv[o][hf*4+2] = wq.z;
            wrv[o][hf*4+3] = wq.w;
        }

    // prefetch first row
    const float* __restrict__ Hl = H + wrow0 * 2048 + lane * 4;
    float4 h[8];
#pragma unroll
    for (int it = 0; it < 8; ++it)
        h[it] = *(const float4*)(Hl + it * 256);

#pragma unroll 1
    for (int rr = 0; rr < 16; ++rr) {
        // fold over l: g[slot] = sum_l sd[l][slot] * H[l][rm(slot)]
        float g[8];
#pragma unroll
        for (int hf = 0; hf < 2; ++hf) {
            g[hf*4+0] = sd[0][hf*4+0]*h[hf].x   + sd[1][hf*4+0]*h[2+hf].x
                      + sd[2][hf*4+0]*h[4+hf].x + sd[3][hf*4+0]*h[6+hf].x;
            g[hf*4+1] = sd[0][hf*4+1]*h[hf].y   + sd[1][hf*4+1]*h[2+hf].y
                      + sd[2][hf*4+1]*h[4+hf].y + sd[3][hf*4+1]*h[6+hf].y;
            g[hf*4+2] = sd[0][hf*4+2]*h[hf].z   + sd[1][hf*4+2]*h[2+hf].z
                      + sd[2][hf*4+2]*h[4+hf].z + sd[3][hf*4+2]*h[6+hf].z;
            g[hf*4+3] = sd[0][hf*4+3]*h[hf].w   + sd[1][hf*4+3]*h[2+hf].w
                      + sd[2][hf*4+3]*h[4+hf].w + sd[3][hf*4+3]*h[6+hf].w;
        }

        // prefetch next row (h dead after fold); wraps on last iter
        {
            const int nrr = (rr + 1) & 15;
            const float* __restrict__ nb = H + (wrow0 + nrr) * 2048 + lane * 4;
#pragma unroll
            for (int it = 0; it < 8; ++it)
                h[it] = *(const float4*)(nb + it * 256);
        }

        // apply W_read slice
        float acc[8];
#pragma unroll
        for (int o = 0; o < 8; ++o) {
            float a = 0.0f;
#pragma unroll
            for (int s = 0; s < 8; ++s) a += wrv[o][s] * g[s];
            acc[o] = a;
        }

        // 6-level butterfly: every lane ends with the full row sums
#pragma unroll
        for (int m = 1; m <= 32; m <<= 1) {
#pragma unroll
            for (int o = 0; o < 8; ++o)
                acc[o] += __shfl_xor(acc[o], m, 64);
        }

        if (lane == rr) {
            float* op = out + (wrow0 + rr) * 8;
            const float4 t0 = *(const float4*)(op);
            const float4 t1 = *(const float4*)(op + 4);
            float4 a0, a1;
            a0.x = acc[0] + t0.x; a0.y = acc[1] + t0.y;
            a0.z = acc[2] + t0.z; a0.w = acc[3] + t0.w;
            a1.x = acc[4] + t1.x; a1.y = acc[5] + t1.y;
            a1.z = acc[6] + t1.z; a1.w = acc[7] + t1.w;
            *(float4*)(op)     = a0;
            *(float4*)(op + 4) = a1;
        }
    }
}

extern "C" void kernel_launch(void* const* d_in, const int* in_sizes, int n_in,
                              void* d_out, int out_size, void* d_ws, size_t ws_size,
                              hipStream_t stream) {
    (void)n_in; (void)d_ws; (void)ws_size; (void)out_size;
    const float* x        = (const float*)d_in[0];
    const float* H        = (const float*)d_in[1];
    const float* W_bit    = (const float*)d_in[2];
    const float* b_bit    = (const float*)d_in[3];
    const float* W_bridge = (const float*)d_in[4];
    const float* W_read   = (const float*)d_in[5];
    const float* b_read   = (const float*)d_in[6];
    const float* W_sh     = (const float*)d_in[7];
    const float* b_sh     = (const float*)d_in[8];
    const float* W_eng    = (const float*)d_in[9];
    const float* b_eng    = (const float*)d_in[10];
    const float* W_imp    = (const float*)d_in[11];
    const float* b_imp    = (const float*)d_in[12];
    const float* W_sur    = (const float*)d_in[13];
    const float* b_sur    = (const float*)d_in[14];
    const float* W_gate   = (const float*)d_in[15];
    const float* b_gate   = (const float*)d_in[16];
    const float* decays   = (const float*)d_in[17];
    const float* halt_w   = (const float*)d_in[18];
    const float* halt_b   = (const float*)d_in[19];
    float* out = (float*)d_out;

    const int B = in_sizes[1] / 2048;            // H is [B, 4*8*16*4]

    // term2 (small net) -> out
    hipLaunchKernelGGL(organism_smallnet, dim3(B / 256), dim3(256), 0, stream,
                       x, W_bit, b_bit, W_bridge, W_read, b_read,
                       W_sh, b_sh, W_eng, b_eng, W_imp, b_imp,
                       W_sur, b_sur, W_gate, b_gate, halt_w, halt_b, out);

    // term1 (H stream) += out
    hipLaunchKernelGGL(organism_stream, dim3(B / 32), dim3(128), 0, stream,
                       H, W_read, decays, out);
}

// Round 4
// 908.321 us; speedup vs baseline: 1.8440x; 1.0562x over previous
//
#include <hip/hip_runtime.h>

__device__ __forceinline__ float sigf(float v) {
    return 1.0f / (1.0f + __expf(-v));
}
__device__ __forceinline__ float tanh_fast(float v) {
    return 1.0f - 2.0f / (__expf(2.0f * v) + 1.0f);
}

// ============================================================================
// Kernel A: per-row small network (term2 + b_read) -> out[row][0..8).
// One thread per row; compute-bound. Isolated from the streaming kernel so its
// ~150-reg live set can't force spills in the memory-bound hot loop.
// ============================================================================
__global__ __launch_bounds__(256)
void organism_smallnet(const float* __restrict__ x,
                       const float* __restrict__ W_bit,
                       const float* __restrict__ b_bit,
                       const float* __restrict__ W_bridge,
                       const float* __restrict__ W_read,
                       const float* __restrict__ b_read,
                       const float* __restrict__ W_sh,
                       const float* __restrict__ b_sh,
                       const float* __restrict__ W_eng,
                       const float* __restrict__ b_eng,
                       const float* __restrict__ W_imp,
                       const float* __restrict__ b_imp,
                       const float* __restrict__ W_sur,
                       const float* __restrict__ b_sur,
                       const float* __restrict__ W_gate,
                       const float* __restrict__ b_gate,
                       const float* __restrict__ halt_w,
                       const float* __restrict__ halt_b,
                       float* __restrict__ out)
{
    const size_t row = (size_t)blockIdx.x * 256 + threadIdx.x;

    float xv[8];
    const float4 x0 = *(const float4*)(x + row * 8);
    const float4 x1 = *(const float4*)(x + row * 8 + 4);
    xv[0]=x0.x; xv[1]=x0.y; xv[2]=x0.z; xv[3]=x0.w;
    xv[4]=x1.x; xv[5]=x1.y; xv[6]=x1.z; xv[7]=x1.w;

    float s1[32];
#pragma unroll
    for (int i = 0; i < 32; ++i) {
        float a = b_bit[i];
#pragma unroll
        for (int k = 0; k < 8; ++k) a += W_bit[i*8+k] * xv[k];
        s1[i] = a;
    }

    float sa = b_sur[0], ga = b_gate[0];
#pragma unroll
    for (int i = 0; i < 32; ++i) {
        sa += W_sur[i]  * s1[i];
        ga += W_gate[i] * s1[i];
    }
    const float sur = sigf(sa) * sigf(ga);

    float s2[64];
#pragma unroll
    for (int m = 0; m < 64; ++m) {
        float a = 0.0f;
#pragma unroll
        for (int i = 0; i < 32; ++i) a += W_bridge[m*32+i] * s1[i];
        s2[m] = tanh_fast(a);
    }

    float ea = b_eng[0], ia = b_imp[0];
    for (int n = 0; n < 64; ++n) {
        float a = b_sh[n];
#pragma unroll
        for (int m = 0; m < 64; ++m) a += W_sh[n*64+m] * s2[m];
        a = fmaxf(a, 0.0f);
        ea += W_eng[n] * a;
        ia += W_imp[n] * a;
    }
    const float eis = 0.25f * sigf(ea) * sigf(ia) * sur;

    float o2[8];
#pragma unroll
    for (int o = 0; o < 8; ++o) o2[o] = b_read[o];
    for (int r = 0; r < 8; ++r) {
        float hs = 0.0f;
#pragma unroll
        for (int l = 0; l < 4; ++l) {
            float a = halt_b[l];
#pragma unroll
            for (int m = 0; m < 64; ++m) a += halt_w[(l*8+r)*64+m] * s2[m];
            hs += sigf(a);
        }
        const float grs = eis * hs;
#pragma unroll
        for (int o = 0; o < 8; ++o) {
            float p = 0.0f;
#pragma unroll
            for (int m = 0; m < 64; ++m) p += W_read[o*512 + r*64 + m] * s2[m];
            o2[o] += grs * p;
        }
    }

    *(float4*)(out + row * 8)     = make_float4(o2[0], o2[1], o2[2], o2[3]);
    *(float4*)(out + row * 8 + 4) = make_float4(o2[4], o2[5], o2[6], o2[7]);
}

// ============================================================================
// Kernel B: streaming H contraction (term1), adds into out.
// Round-0 structure (64-thread blocks, 32 rows/wave, grid B/32 = 2048,
// 8 waves/CU) but DEPTH-2 register pipeline: hA/hB double buffer keeps two
// rows (16 KB) in flight per wave. Statically indexed (rule #20: no runtime
// indexing of float4 arrays). Live set ~184 VGPR << 256: no spill possible,
// occupancy same 8 waves/CU as round 0 -> single-variable test of the
// per-wave-MLP theory vs a read-service-rate cap.
// ============================================================================
__device__ __forceinline__ void process_row(
    float4 (&h)[8],                       // this row's data; refilled w/ row rr+2
    const float (&sd)[4][8],
    const float (&wrv)[8][8],
    const float* __restrict__ Hlane,      // H + row0*2048 + lane*4
    int rr, int lane,
    float* __restrict__ outblk)           // out + row0*8
{
    // fold over l: g[slot] = sum_l sd[l][slot] * H[l][rm(slot)]
    float g[8];
#pragma unroll
    for (int hf = 0; hf < 2; ++hf) {
        g[hf*4+0] = sd[0][hf*4+0]*h[hf].x   + sd[1][hf*4+0]*h[2+hf].x
                  + sd[2][hf*4+0]*h[4+hf].x + sd[3][hf*4+0]*h[6+hf].x;
        g[hf*4+1] = sd[0][hf*4+1]*h[hf].y   + sd[1][hf*4+1]*h[2+hf].y
                  + sd[2][hf*4+1]*h[4+hf].y + sd[3][hf*4+1]*h[6+hf].y;
        g[hf*4+2] = sd[0][hf*4+2]*h[hf].z   + sd[1][hf*4+2]*h[2+hf].z
                  + sd[2][hf*4+2]*h[4+hf].z + sd[3][hf*4+2]*h[6+hf].z;
        g[hf*4+3] = sd[0][hf*4+3]*h[hf].w   + sd[1][hf*4+3]*h[2+hf].w
                  + sd[2][hf*4+3]*h[4+hf].w + sd[3][hf*4+3]*h[6+hf].w;
    }

    // refill this buffer with row rr+2 (mod 32); h is dead after the fold
    {
        const float* __restrict__ nb = Hlane + (size_t)((rr + 2) & 31) * 2048;
#pragma unroll
        for (int it = 0; it < 8; ++it)
            h[it] = *(const float4*)(nb + it * 256);
    }

    // apply W_read slice
    float acc[8];
#pragma unroll
    for (int o = 0; o < 8; ++o) {
        float a = 0.0f;
#pragma unroll
        for (int s = 0; s < 8; ++s) a += wrv[o][s] * g[s];
        acc[o] = a;
    }

    // 6-level butterfly: every lane ends with the full row sums
#pragma unroll
    for (int m = 1; m <= 32; m <<= 1) {
#pragma unroll
        for (int o = 0; o < 8; ++o)
            acc[o] += __shfl_xor(acc[o], m, 64);
    }

    if (lane == rr) {
        float* op = outblk + (size_t)rr * 8;
        const float4 t0 = *(const float4*)(op);
        const float4 t1 = *(const float4*)(op + 4);
        float4 a0, a1;
        a0.x = acc[0] + t0.x; a0.y = acc[1] + t0.y;
        a0.z = acc[2] + t0.z; a0.w = acc[3] + t0.w;
        a1.x = acc[4] + t1.x; a1.y = acc[5] + t1.y;
        a1.z = acc[6] + t1.z; a1.w = acc[7] + t1.w;
        *(float4*)(op)     = a0;
        *(float4*)(op + 4) = a1;
    }
}

__global__ __launch_bounds__(64)
void organism_stream(const float* __restrict__ H,
                     const float* __restrict__ W_read,
                     const float* __restrict__ decays,
                     float* __restrict__ out)
{
    const int lane = threadIdx.x;            // 0..63
    const size_t row0 = (size_t)blockIdx.x * 32;

    // per-lane constants: slot s = hf*4+c  <->  rm = hf*256 + lane*4 + c
    float sd[4][8];
#pragma unroll
    for (int l = 0; l < 4; ++l)
#pragma unroll
        for (int hf = 0; hf < 2; ++hf) {
            const float4 d = *(const float4*)(decays + l*512 + hf*256 + lane*4);
            sd[l][hf*4+0] = 0.25f * sigf(d.x);
            sd[l][hf*4+1] = 0.25f * sigf(d.y);
            sd[l][hf*4+2] = 0.25f * sigf(d.z);
            sd[l][hf*4+3] = 0.25f * sigf(d.w);
        }
    float wrv[8][8];
#pragma unroll
    for (int o = 0; o < 8; ++o)
#pragma unroll
        for (int hf = 0; hf < 2; ++hf) {
            const float4 wq = *(const float4*)(W_read + o*512 + hf*256 + lane*4);
            wrv[o][hf*4+0] = wq.x;
            wrv[o][hf*4+1] = wq.y;
            wrv[o][hf*4+2] = wq.z;
            wrv[o][hf*4+3] = wq.w;
        }

    const float* __restrict__ Hlane = H + row0 * 2048 + lane * 4;
    float* __restrict__ outblk = out + row0 * 8;

    // prologue: rows 0 and 1 in flight
    float4 hA[8], hB[8];
#pragma unroll
    for (int it = 0; it < 8; ++it)
        hA[it] = *(const float4*)(Hlane + it * 256);
#pragma unroll
    for (int it = 0; it < 8; ++it)
        hB[it] = *(const float4*)(Hlane + 2048 + it * 256);

#pragma unroll 1
    for (int i2 = 0; i2 < 16; ++i2) {
        process_row(hA, sd, wrv, Hlane, 2*i2,     lane, outblk);
        process_row(hB, sd, wrv, Hlane, 2*i2 + 1, lane, outblk);
    }
}

extern "C" void kernel_launch(void* const* d_in, const int* in_sizes, int n_in,
                              void* d_out, int out_size, void* d_ws, size_t ws_size,
                              hipStream_t stream) {
    (void)n_in; (void)d_ws; (void)ws_size; (void)out_size;
    const float* x        = (const float*)d_in[0];
    const float* H        = (const float*)d_in[1];
    const float* W_bit    = (const float*)d_in[2];
    const float* b_bit    = (const float*)d_in[3];
    const float* W_bridge = (const float*)d_in[4];
    const float* W_read   = (const float*)d_in[5];
    const float* b_read   = (const float*)d_in[6];
    const float* W_sh     = (const float*)d_in[7];
    const float* b_sh     = (const float*)d_in[8];
    const float* W_eng    = (const float*)d_in[9];
    const float* b_eng    = (const float*)d_in[10];
    const float* W_imp    = (const float*)d_in[11];
    const float* b_imp    = (const float*)d_in[12];
    const float* W_sur    = (const float*)d_in[13];
    const float* b_sur    = (const float*)d_in[14];
    const float* W_gate   = (const float*)d_in[15];
    const float* b_gate   = (const float*)d_in[16];
    const float* decays   = (const float*)d_in[17];
    const float* halt_w   = (const float*)d_in[18];
    const float* halt_b   = (const float*)d_in[19];
    float* out = (float*)d_out;

    const int B = in_sizes[1] / 2048;            // H is [B, 4*8*16*4]

    // term2 (small net) -> out
    hipLaunchKernelGGL(organism_smallnet, dim3(B / 256), dim3(256), 0, stream,
                       x, W_bit, b_bit, W_bridge, W_read, b_read,
                       W_sh, b_sh, W_eng, b_eng, W_imp, b_imp,
                       W_sur, b_sur, W_gate, b_gate, halt_w, halt_b, out);

    // term1 (H stream) += out
    hipLaunchKernelGGL(organism_stream, dim3(B / 32), dim3(64), 0, stream,
                       H, W_read, decays, out);
}